// Round 13
// baseline (912.238 us; speedup 1.0000x reference)
//
#include <hip/hip_runtime.h>
#include <hip/hip_bf16.h>

#define NTOK 1024
#define HDIM 2880
#define IDIM 2880
#define NEXP 8
#define BK 64
#define NT 45  // HDIM/BK

typedef __attribute__((ext_vector_type(4))) float fx4;
typedef __attribute__((ext_vector_type(8))) short sx8;
typedef __attribute__((ext_vector_type(8))) unsigned short usx8;

typedef const __attribute__((address_space(1))) void* gas_p;
typedef __attribute__((address_space(3))) void* las_p;

__device__ __forceinline__ unsigned short f2bf(float f) {
  __hip_bfloat16 b = __float2bfloat16(f);
  return __builtin_bit_cast(unsigned short, b);
}
__device__ __forceinline__ usx8 cvt8(fx4 a, fx4 b) {
  usx8 u = {f2bf(a.x), f2bf(a.y), f2bf(a.z), f2bf(a.w),
            f2bf(b.x), f2bf(b.y), f2bf(b.z), f2bf(b.w)};
  return u;
}

#define MFMA16(a, b, c) __builtin_amdgcn_mfma_f32_16x16x32_bf16(a, b, c, 0, 0, 0)
#define VMCNT0 asm volatile("s_waitcnt vmcnt(0)" ::: "memory")

__global__ __launch_bounds__(256) void init_out_k(const float* __restrict__ x,
                                                  float* __restrict__ out) {
  int i = blockIdx.x * 256 + threadIdx.x;
  ((fx4*)out)[i] = ((const fx4*)x)[i];
}

// streaming fp32 -> bf16 (n8 = elements/8)
__global__ __launch_bounds__(256) void cvt_bf_k(const float* __restrict__ src,
                                                unsigned short* __restrict__ dst,
                                                long n8) {
  const long stride = (long)gridDim.x * 256;
  for (long i = (long)blockIdx.x * 256 + threadIdx.x; i < n8; i += stride) {
    fx4 a = *(const fx4*)(src + i * 8);
    fx4 b = *(const fx4*)(src + i * 8 + 4);
    *(usx8*)(dst + i * 8) = cvt8(a, b);
  }
}

__global__ __launch_bounds__(256) void rms_router_k(
    const float* __restrict__ x, const float* __restrict__ norm_w,
    const float* __restrict__ gate_w, const float* __restrict__ gate_b,
    unsigned short* __restrict__ t_bf, int* __restrict__ cnt,
    int* __restrict__ tok, float* __restrict__ wgt) {
  const int n = blockIdx.x;
  const int tid = threadIdx.x;
  const int wid = tid >> 6, lane = tid & 63;
  const float* xr = x + (size_t)n * HDIM;

  float ss = 0.f;
  for (int h = tid; h < HDIM; h += 256) { float v = xr[h]; ss += v * v; }
  #pragma unroll
  for (int o = 32; o > 0; o >>= 1) ss += __shfl_down(ss, o);
  __shared__ float sred[4];
  if (lane == 0) sred[wid] = ss;
  __syncthreads();
  const float rstd =
      rsqrtf((sred[0] + sred[1] + sred[2] + sred[3]) * (1.0f / HDIM) + 1e-5f);

  float p[NEXP];
  #pragma unroll
  for (int e = 0; e < NEXP; e++) p[e] = 0.f;
  for (int h = tid; h < HDIM; h += 256) {
    float xv = xr[h] * norm_w[h];
    t_bf[(size_t)n * HDIM + h] = f2bf(xv * rstd);
    #pragma unroll
    for (int e = 0; e < NEXP; e++) p[e] += xv * gate_w[e * HDIM + h];
  }
  __shared__ float pls[4][NEXP];
  #pragma unroll
  for (int e = 0; e < NEXP; e++) {
    float v = p[e];
    #pragma unroll
    for (int o = 32; o > 0; o >>= 1) v += __shfl_down(v, o);
    if (lane == 0) pls[wid][e] = v;
  }
  __syncthreads();
  if (tid == 0) {
    float lg[NEXP];
    #pragma unroll
    for (int e = 0; e < NEXP; e++)
      lg[e] = (pls[0][e] + pls[1][e] + pls[2][e] + pls[3][e]) * rstd + gate_b[e];
    unsigned used = 0;
    float val[4];
    int idx[4];
    for (int k = 0; k < 4; k++) {
      float best = -1e30f;
      int bi = 0;
      for (int e = 0; e < NEXP; e++)
        if (!((used >> e) & 1u) && lg[e] > best) { best = lg[e]; bi = e; }
      used |= 1u << bi;
      val[k] = best;
      idx[k] = bi;
    }
    float sum = 0.f, w[4];
    for (int k = 0; k < 4; k++) { w[k] = expf(val[k] - val[0]); sum += w[k]; }
    for (int k = 0; k < 4; k++) {
      int e = idx[k];
      int slot = atomicAdd(&cnt[e], 1);
      tok[e * NTOK + slot] = n;
      wgt[e * NTOK + slot] = w[k] / sum;
    }
  }
}

// GEMM1: 256 tokens x 96 I-cols x {G,L}, BK=64, 8 waves (4m x 2n), LDS dbuf
// 112 KB (1 block/CU). T3-minimum pipeline: issue DMA(t+1) early -> compute(t)
// -> vmcnt(0) (old loads) -> ONE barrier. Verified 0-conflict XOR swizzle.
template <bool BF16B>
__global__ __launch_bounds__(512, 2) void gemm1_k(
    const unsigned short* __restrict__ t_bf,
    const unsigned short* __restrict__ wgu_bf,
    const float* __restrict__ w_gate_up, const float* __restrict__ b_gate_up,
    const int* __restrict__ cnt, const int* __restrict__ tok,
    unsigned short* __restrict__ act_bf) {
  const int h = blockIdx.x;
  const int g = h >> 5, z = (h >> 3) & 3, v = h & 7;
  const int u = g * 8 + v;        // < 240
  const int e = u / 30;
  const int c0 = (u % 30) * 96;   // 30 slices x 96 I-cols
  const int m0 = z * 256;
  const int ce = cnt[e];
  if (m0 >= ce) return;

  const int tid = threadIdx.x, lane = tid & 63, wid = tid >> 6;
  const int fr = lane & 15, fq = lane >> 4;
  const int wm = wid >> 1, wn = wid & 1;
  const int sw = ((lane & 7) ^ ((lane >> 3) & 7)) * 8;

  __shared__ __align__(16) unsigned short Ash[2][256 * 64];  // 64 KB
  __shared__ __align__(16) unsigned short Bsh[2][192 * 64];  // 48 KB (G:0-95 L:96-191)

  const fx4 FZ = {0.f, 0.f, 0.f, 0.f};
  fx4 accG[4][3], accL[4][3];
  #pragma unroll
  for (int m = 0; m < 4; m++)
    #pragma unroll
    for (int n = 0; n < 3; n++) { accG[m][n] = FZ; accL[m][n] = FZ; }

  const unsigned short* gA[4];
  #pragma unroll
  for (int j = 0; j < 4; ++j) {
    int R = m0 + wid * 32 + j * 8 + (lane >> 3);
    int rc = R < ce ? R : ce - 1;
    gA[j] = t_bf + (size_t)tok[e * NTOK + rc] * HDIM + sw;
  }
  const unsigned short* gB[3];
  #pragma unroll
  for (int j = 0; j < 3; ++j) {
    int br = wid * 24 + j * 8 + (lane >> 3);
    int wr = br < 96 ? (c0 + br) : (IDIM + c0 + (br - 96));
    gB[j] = wgu_bf + ((size_t)e * (2 * IDIM) + wr) * HDIM + sw;
  }
  const float* fB[3];
  int fRow[3], fCh[3];
  if constexpr (!BF16B) {
    #pragma unroll
    for (int q = 0; q < 3; ++q) {
      int s = tid + 512 * q;  // 1536 slots = 192 rows x 8 chunks
      fRow[q] = s >> 3;
      fCh[q] = s & 7;
      int wr = fRow[q] < 96 ? (c0 + fRow[q]) : (IDIM + c0 + (fRow[q] - 96));
      fB[q] = w_gate_up + ((size_t)e * (2 * IDIM) + wr) * HDIM + fCh[q] * 8;
    }
  }

  fx4 Ra[6];
  #define G1_DMA_A(kt, bb)                                                     \
    {                                                                          \
      _Pragma("unroll") for (int j = 0; j < 4; ++j)                            \
          __builtin_amdgcn_global_load_lds(                                    \
              (gas_p)(gA[j] + (size_t)(kt)*BK),                                \
              (las_p)&Ash[bb][(wid * 32 + j * 8) * 64], 16, 0, 0);             \
    }
  #define G1_DMA_B(kt, bb)                                                     \
    {                                                                          \
      _Pragma("unroll") for (int j = 0; j < 3; ++j)                            \
          __builtin_amdgcn_global_load_lds(                                    \
              (gas_p)(gB[j] + (size_t)(kt)*BK),                                \
              (las_p)&Bsh[bb][(wid * 24 + j * 8) * 64], 16, 0, 0);             \
    }
  #define G1_FLOAD(kt)                                                         \
    {                                                                          \
      _Pragma("unroll") for (int q = 0; q < 3; ++q) {                          \
        Ra[2 * q] = *(const fx4*)(fB[q] + (size_t)(kt)*BK);                    \
        Ra[2 * q + 1] = *(const fx4*)(fB[q] + (size_t)(kt)*BK + 4);            \
      }                                                                        \
    }
  #define G1_FWRITE(bb)                                                        \
    {                                                                          \
      _Pragma("unroll") for (int q = 0; q < 3; ++q)                            \
          *(usx8*)&Bsh[bb][fRow[q] * 64 + ((fCh[q] ^ (fRow[q] & 7)) * 8)] =    \
              cvt8(Ra[2 * q], Ra[2 * q + 1]);                                  \
    }
  #define G1_COMPUTE(bb)                                                       \
    {                                                                          \
      _Pragma("unroll") for (int ks = 0; ks < 2; ++ks) {                       \
        const int rk = ks * 4 + fq;                                            \
        sx8 aF[4], bG[3], bL[3];                                               \
        _Pragma("unroll") for (int m = 0; m < 4; ++m) aF[m] =                  \
            *(const sx8*)&Ash[bb][(wm * 64 + m * 16 + fr) * 64 +               \
                                  ((rk ^ (fr & 7)) * 8)];                      \
        _Pragma("unroll") for (int n = 0; n < 3; ++n) {                        \
          bG[n] = *(const sx8*)&Bsh[bb][(wn * 48 + n * 16 + fr) * 64 +         \
                                        ((rk ^ (fr & 7)) * 8)];                \
          bL[n] = *(const sx8*)&Bsh[bb][(96 + wn * 48 + n * 16 + fr) * 64 +    \
                                        ((rk ^ (fr & 7)) * 8)];                \
        }                                                                      \
        __builtin_amdgcn_s_setprio(1);                                         \
        _Pragma("unroll") for (int n = 0; n < 3; ++n)                          \
            _Pragma("unroll") for (int m = 0; m < 4; ++m) {                    \
          accG[m][n] = MFMA16(aF[m], bG[n], accG[m][n]);                       \
          accL[m][n] = MFMA16(aF[m], bL[n], accL[m][n]);                       \
        }                                                                      \
        __builtin_amdgcn_s_setprio(0);                                         \
      }                                                                        \
    }

  // prologue: stage tile 0 into buf 0
  G1_DMA_A(0, 0);
  if constexpr (BF16B) {
    G1_DMA_B(0, 0);
  } else {
    G1_FLOAD(0);
    G1_FWRITE(0);
  }
  VMCNT0;
  __syncthreads();

  int p = 0;
  for (int t = 0; t < NT; ++t) {
    if (t + 1 < NT) {
      G1_DMA_A(t + 1, p ^ 1);
      if constexpr (BF16B) {
        G1_DMA_B(t + 1, p ^ 1);
      } else {
        G1_FLOAD(t + 1);
      }
    }
    G1_COMPUTE(p);
    if constexpr (!BF16B) {
      if (t + 1 < NT) G1_FWRITE(p ^ 1);
    }
    VMCNT0;  // waits loads issued BEFORE compute -> cheap
    __syncthreads();
    p ^= 1;
  }

  #pragma unroll
  for (int n = 0; n < 3; ++n) {
    const int col = c0 + wn * 48 + n * 16 + fr;
    const float bg = b_gate_up[e * (2 * IDIM) + col];
    const float bl = b_gate_up[e * (2 * IDIM) + IDIM + col];
    #pragma unroll
    for (int m = 0; m < 4; ++m) {
      #pragma unroll
      for (int r = 0; r < 4; ++r) {
        int slot = m0 + wm * 64 + m * 16 + fq * 4 + r;
        if (slot < ce) {
          float gv = accG[m][n][r] + bg;
          float lv = accL[m][n][r] + bl;
          float a = gv * (1.0f / (1.0f + __expf(-1.702f * gv))) * (lv + 1.0f);
          act_bf[((size_t)e * NTOK + slot) * IDIM + col] = f2bf(a);
        }
      }
    }
  }
}

// GEMM2: 256 rows x 192 cols, BK=64, 8 waves (4m x 2n), same T3-min pipeline.
template <bool BF16B>
__global__ __launch_bounds__(512, 2) void gemm2_k(
    const unsigned short* __restrict__ act_bf,
    const unsigned short* __restrict__ wd_bf, const float* __restrict__ w_down,
    const float* __restrict__ b_down, const int* __restrict__ cnt,
    const int* __restrict__ tok, const float* __restrict__ wgt,
    float* __restrict__ out) {
  const int h = blockIdx.x;
  const int g = h >> 5, z = (h >> 3) & 3, v = h & 7;
  const int u = g * 8 + v;            // < 120
  const int e = u / 15;
  const int c0 = (u % 15) * 192;
  const int m0 = z * 256;
  const int ce = cnt[e];
  if (m0 >= ce) return;

  const int tid = threadIdx.x, lane = tid & 63, wid = tid >> 6;
  const int fr = lane & 15, fq = lane >> 4;
  const int wm = wid >> 1, wn = wid & 1;
  const int sw = ((lane & 7) ^ ((lane >> 3) & 7)) * 8;

  __shared__ __align__(16) unsigned short Ash[2][256 * 64];  // 64 KB
  __shared__ __align__(16) unsigned short Bsh[2][192 * 64];  // 48 KB

  const fx4 FZ = {0.f, 0.f, 0.f, 0.f};
  fx4 acc[4][6];
  #pragma unroll
  for (int m = 0; m < 4; m++)
    #pragma unroll
    for (int n = 0; n < 6; n++) acc[m][n] = FZ;

  const unsigned short* gA[4];
  #pragma unroll
  for (int j = 0; j < 4; ++j) {
    int R = m0 + wid * 32 + j * 8 + (lane >> 3);
    int rc = R < ce ? R : ce - 1;
    gA[j] = act_bf + ((size_t)e * NTOK + rc) * IDIM + sw;
  }
  const unsigned short* gB[3];
  #pragma unroll
  for (int j = 0; j < 3; ++j) {
    int br = wid * 24 + j * 8 + (lane >> 3);
    gB[j] = wd_bf + ((size_t)e * HDIM + c0 + br) * IDIM + sw;
  }
  const float* fB[3];
  int fRow[3], fCh[3];
  if constexpr (!BF16B) {
    #pragma unroll
    for (int q = 0; q < 3; ++q) {
      int s = tid + 512 * q;
      fRow[q] = s >> 3;
      fCh[q] = s & 7;
      fB[q] = w_down + ((size_t)e * HDIM + c0 + fRow[q]) * IDIM + fCh[q] * 8;
    }
  }

  fx4 Ra[6];
  #define G2_DMA_A(kt, bb)                                                     \
    {                                                                          \
      _Pragma("unroll") for (int j = 0; j < 4; ++j)                            \
          __builtin_amdgcn_global_load_lds(                                    \
              (gas_p)(gA[j] + (size_t)(kt)*BK),                                \
              (las_p)&Ash[bb][(wid * 32 + j * 8) * 64], 16, 0, 0);             \
    }
  #define G2_DMA_B(kt, bb)                                                     \
    {                                                                          \
      _Pragma("unroll") for (int j = 0; j < 3; ++j)                            \
          __builtin_amdgcn_global_load_lds(                                    \
              (gas_p)(gB[j] + (size_t)(kt)*BK),                                \
              (las_p)&Bsh[bb][(wid * 24 + j * 8) * 64], 16, 0, 0);             \
    }
  #define G2_FLOAD(kt)                                                         \
    {                                                                          \
      _Pragma("unroll") for (int q = 0; q < 3; ++q) {                          \
        Ra[2 * q] = *(const fx4*)(fB[q] + (size_t)(kt)*BK);                    \
        Ra[2 * q + 1] = *(const fx4*)(fB[q] + (size_t)(kt)*BK + 4);            \
      }                                                                        \
    }
  #define G2_FWRITE(bb)                                                        \
    {                                                                          \
      _Pragma("unroll") for (int q = 0; q < 3; ++q)                            \
          *(usx8*)&Bsh[bb][fRow[q] * 64 + ((fCh[q] ^ (fRow[q] & 7)) * 8)] =    \
              cvt8(Ra[2 * q], Ra[2 * q + 1]);                                  \
    }
  #define G2_COMPUTE(bb)                                                       \
    {                                                                          \
      _Pragma("unroll") for (int ks = 0; ks < 2; ++ks) {                       \
        const int rk = ks * 4 + fq;                                            \
        sx8 aF[4], bB[6];                                                      \
        _Pragma("unroll") for (int m = 0; m < 4; ++m) aF[m] =                  \
            *(const sx8*)&Ash[bb][(wm * 64 + m * 16 + fr) * 64 +               \
                                  ((rk ^ (fr & 7)) * 8)];                      \
        _Pragma("unroll") for (int n = 0; n < 6; ++n) bB[n] =                  \
            *(const sx8*)&Bsh[bb][(wn * 96 + n * 16 + fr) * 64 +               \
                                  ((rk ^ (fr & 7)) * 8)];                      \
        __builtin_amdgcn_s_setprio(1);                                         \
        _Pragma("unroll") for (int n = 0; n < 6; ++n)                          \
            _Pragma("unroll") for (int m = 0; m < 4; ++m)                      \
                acc[m][n] = MFMA16(aF[m], bB[n], acc[m][n]);                   \
        __builtin_amdgcn_s_setprio(0);                                         \
      }                                                                        \
    }

  G2_DMA_A(0, 0);
  if constexpr (BF16B) {
    G2_DMA_B(0, 0);
  } else {
    G2_FLOAD(0);
    G2_FWRITE(0);
  }
  VMCNT0;
  __syncthreads();

  int p = 0;
  for (int t = 0; t < NT; ++t) {
    if (t + 1 < NT) {
      G2_DMA_A(t + 1, p ^ 1);
      if constexpr (BF16B) {
        G2_DMA_B(t + 1, p ^ 1);
      } else {
        G2_FLOAD(t + 1);
      }
    }
    G2_COMPUTE(p);
    if constexpr (!BF16B) {
      if (t + 1 < NT) G2_FWRITE(p ^ 1);
    }
    VMCNT0;
    __syncthreads();
    p ^= 1;
  }

  #pragma unroll
  for (int n = 0; n < 6; ++n) {
    const int col = c0 + wn * 96 + n * 16 + fr;
    const float bias = b_down[e * HDIM + col];
    #pragma unroll
    for (int m = 0; m < 4; ++m) {
      #pragma unroll
      for (int r = 0; r < 4; ++r) {
        int slot = m0 + wm * 64 + m * 16 + fq * 4 + r;
        if (slot < ce) {
          int token = tok[e * NTOK + slot];
          float w = wgt[e * NTOK + slot];
          atomicAdd(&out[(size_t)token * HDIM + col], w * (acc[m][n][r] + bias));
        }
      }
    }
  }
}

extern "C" void kernel_launch(void* const* d_in, const int* in_sizes, int n_in,
                              void* d_out, int out_size, void* d_ws,
                              size_t ws_size, hipStream_t stream) {
  const float* x = (const float*)d_in[0];
  const float* norm_w = (const float*)d_in[1];
  const float* gate_w = (const float*)d_in[2];
  const float* gate_b = (const float*)d_in[3];
  const float* w_gate_up = (const float*)d_in[4];
  const float* b_gate_up = (const float*)d_in[5];
  const float* w_down = (const float*)d_in[6];
  const float* b_down = (const float*)d_in[7];
  float* out = (float*)d_out;

  char* ws = (char*)d_ws;
  size_t off = 0;
  unsigned short* t_bf = (unsigned short*)(ws + off);
  off += (size_t)NTOK * HDIM * 2;
  unsigned short* act_bf = (unsigned short*)(ws + off);
  off += (size_t)NEXP * NTOK * IDIM * 2;
  int* cnt = (int*)(ws + off);
  off += 256;
  int* tok = (int*)(ws + off);
  off += (size_t)NEXP * NTOK * 4;
  float* wgt = (float*)(ws + off);
  off += (size_t)NEXP * NTOK * 4;

  const size_t WD_E = (size_t)NEXP * HDIM * IDIM;
  const size_t WGU_E = (size_t)NEXP * 2 * IDIM * HDIM;
  unsigned short* wd_bf = (unsigned short*)(ws + off);
  const bool haveWd = (off + WD_E * 2) <= ws_size;
  if (haveWd) off += WD_E * 2;
  unsigned short* wgu_bf = (unsigned short*)(ws + off);
  const bool haveWgu = (off + WGU_E * 2) <= ws_size;

  hipMemsetAsync(cnt, 0, NEXP * sizeof(int), stream);
  init_out_k<<<2880, 256, 0, stream>>>(x, out);
  if (haveWgu)
    cvt_bf_k<<<4096, 256, 0, stream>>>(w_gate_up, wgu_bf, (long)(WGU_E / 8));
  if (haveWd)
    cvt_bf_k<<<4096, 256, 0, stream>>>(w_down, wd_bf, (long)(WD_E / 8));
  rms_router_k<<<NTOK, 256, 0, stream>>>(x, norm_w, gate_w, gate_b, t_bf, cnt,
                                         tok, wgt);
  // h = g*32 + z*8 + v: z-twins of one (e,c) share h%8 (same XCD), 8 apart.
  if (haveWgu)
    gemm1_k<true><<<960, 512, 0, stream>>>(t_bf, wgu_bf, w_gate_up, b_gate_up,
                                           cnt, tok, act_bf);
  else
    gemm1_k<false><<<960, 512, 0, stream>>>(t_bf, nullptr, w_gate_up,
                                            b_gate_up, cnt, tok, act_bf);
  if (haveWd)
    gemm2_k<true><<<480, 512, 0, stream>>>(act_bf, wd_bf, w_down, b_down, cnt,
                                           tok, wgt, out);
  else
    gemm2_k<false><<<480, 512, 0, stream>>>(act_bf, nullptr, w_down, b_down,
                                            cnt, tok, wgt, out);
}

// Round 14
// 770.287 us; speedup vs baseline: 1.1843x; 1.1843x over previous
//
#include <hip/hip_runtime.h>
#include <hip/hip_bf16.h>

#define NTOK 1024
#define HDIM 2880
#define IDIM 2880
#define NEXP 8
#define BK 64
#define NT 45  // HDIM/BK

typedef __attribute__((ext_vector_type(4))) float fx4;
typedef __attribute__((ext_vector_type(8))) short sx8;
typedef __attribute__((ext_vector_type(8))) unsigned short usx8;

typedef const __attribute__((address_space(1))) void* gas_p;
typedef __attribute__((address_space(3))) void* las_p;

__device__ __forceinline__ unsigned short f2bf(float f) {
  __hip_bfloat16 b = __float2bfloat16(f);
  return __builtin_bit_cast(unsigned short, b);
}
__device__ __forceinline__ usx8 cvt8(fx4 a, fx4 b) {
  usx8 u = {f2bf(a.x), f2bf(a.y), f2bf(a.z), f2bf(a.w),
            f2bf(b.x), f2bf(b.y), f2bf(b.z), f2bf(b.w)};
  return u;
}

#define MFMA16(a, b, c) __builtin_amdgcn_mfma_f32_16x16x32_bf16(a, b, c, 0, 0, 0)

__global__ __launch_bounds__(256) void init_out_k(const float* __restrict__ x,
                                                  float* __restrict__ out) {
  int i = blockIdx.x * 256 + threadIdx.x;
  ((fx4*)out)[i] = ((const fx4*)x)[i];
}

__global__ __launch_bounds__(256) void rms_router_k(
    const float* __restrict__ x, const float* __restrict__ norm_w,
    const float* __restrict__ gate_w, const float* __restrict__ gate_b,
    unsigned short* __restrict__ t_bf, int* __restrict__ cnt,
    int* __restrict__ tok, float* __restrict__ wgt) {
  const int n = blockIdx.x;
  const int tid = threadIdx.x;
  const int wid = tid >> 6, lane = tid & 63;
  const float* xr = x + (size_t)n * HDIM;

  float ss = 0.f;
  for (int h = tid; h < HDIM; h += 256) { float v = xr[h]; ss += v * v; }
  #pragma unroll
  for (int o = 32; o > 0; o >>= 1) ss += __shfl_down(ss, o);
  __shared__ float sred[4];
  if (lane == 0) sred[wid] = ss;
  __syncthreads();
  const float rstd =
      rsqrtf((sred[0] + sred[1] + sred[2] + sred[3]) * (1.0f / HDIM) + 1e-5f);

  float p[NEXP];
  #pragma unroll
  for (int e = 0; e < NEXP; e++) p[e] = 0.f;
  for (int h = tid; h < HDIM; h += 256) {
    float xv = xr[h] * norm_w[h];
    t_bf[(size_t)n * HDIM + h] = f2bf(xv * rstd);
    #pragma unroll
    for (int e = 0; e < NEXP; e++) p[e] += xv * gate_w[e * HDIM + h];
  }
  __shared__ float pls[4][NEXP];
  #pragma unroll
  for (int e = 0; e < NEXP; e++) {
    float v = p[e];
    #pragma unroll
    for (int o = 32; o > 0; o >>= 1) v += __shfl_down(v, o);
    if (lane == 0) pls[wid][e] = v;
  }
  __syncthreads();
  if (tid == 0) {
    float lg[NEXP];
    #pragma unroll
    for (int e = 0; e < NEXP; e++)
      lg[e] = (pls[0][e] + pls[1][e] + pls[2][e] + pls[3][e]) * rstd + gate_b[e];
    unsigned used = 0;
    float val[4];
    int idx[4];
    for (int k = 0; k < 4; k++) {
      float best = -1e30f;
      int bi = 0;
      for (int e = 0; e < NEXP; e++)
        if (!((used >> e) & 1u) && lg[e] > best) { best = lg[e]; bi = e; }
      used |= 1u << bi;
      val[k] = best;
      idx[k] = bi;
    }
    float sum = 0.f, w[4];
    for (int k = 0; k < 4; k++) { w[k] = expf(val[k] - val[0]); sum += w[k]; }
    for (int k = 0; k < 4; k++) {
      int e = idx[k];
      int slot = atomicAdd(&cnt[e], 1);
      tok[e * NTOK + slot] = n;
      wgt[e * NTOK + slot] = w[k] / sum;
    }
  }
}

// GEMM1: BM=512 (all of one expert; m-loop for overflow) x 64 I-cols x {G,L}.
// B fp32 read ONCE globally per block (no twins), converted in-loop (tiny).
// A bf16 via global_load_lds, L2-resident per XCD (e = h&7).
// m97 2-barrier schedule; B(t+1) fp32 reg-load issued after drain barrier.
__global__ __launch_bounds__(512, 1) void gemm1_k(
    const unsigned short* __restrict__ t_bf,
    const float* __restrict__ w_gate_up, const float* __restrict__ b_gate_up,
    const int* __restrict__ cnt, const int* __restrict__ tok,
    unsigned short* __restrict__ act_bf) {
  const int h = blockIdx.x;
  const int e = h & 7;            // round-robin XCDs; same-e blocks 8 apart
  const int c0 = (h >> 3) * 64;   // 45 slices x 64 I-cols
  const int ce = cnt[e];

  const int tid = threadIdx.x, lane = tid & 63, wid = tid >> 6;
  const int fr = lane & 15, fq = lane >> 4;
  const int wm = wid >> 1, wn = wid & 1;  // 4m x 2n
  const int sw = ((lane & 7) ^ ((lane >> 3) & 7)) * 8;

  __shared__ __align__(16) unsigned short Ash[512 * 64];  // 64 KB
  __shared__ __align__(16) unsigned short Bsh[128 * 64];  // 16 KB (G:0-63 L:64-127)

  // B fp32 sources: slot tid -> G row tid>>3; slot tid+512 -> L row (tid>>3)
  const int bR = tid >> 3, bC = tid & 7;
  const float* wb = w_gate_up + (size_t)e * (2 * IDIM) * HDIM;
  const float* srcG = wb + (size_t)(c0 + bR) * HDIM + bC * 8;
  const float* srcL = wb + (size_t)(IDIM + c0 + bR) * HDIM + bC * 8;
  const int bwG = bR * 64 + ((bC ^ (bR & 7)) * 8);
  const int bwL = (64 + bR) * 64 + ((bC ^ ((64 + bR) & 7)) * 8);

  for (int m0 = 0; m0 < ce; m0 += 512) {
    // A gather bases for this row-chunk
    const unsigned short* gA[8];
    #pragma unroll
    for (int j = 0; j < 8; ++j) {
      int R = m0 + wid * 64 + j * 8 + (lane >> 3);
      int rc = R < ce ? R : ce - 1;
      gA[j] = t_bf + (size_t)tok[e * NTOK + rc] * HDIM + sw;
    }
    const fx4 FZ = {0.f, 0.f, 0.f, 0.f};
    fx4 accG[8][2], accL[8][2];
    #pragma unroll
    for (int m = 0; m < 8; m++)
      #pragma unroll
      for (int n = 0; n < 2; n++) { accG[m][n] = FZ; accL[m][n] = FZ; }

    fx4 rg0 = *(const fx4*)(srcG), rg1 = *(const fx4*)(srcG + 4);
    fx4 rl0 = *(const fx4*)(srcL), rl1 = *(const fx4*)(srcL + 4);

    for (int t = 0; t < NT; ++t) {
      const int ko = t * BK;
      __syncthreads();  // previous tile fully consumed
      #pragma unroll
      for (int j = 0; j < 8; ++j)
        __builtin_amdgcn_global_load_lds(
            (gas_p)(gA[j] + ko), (las_p)&Ash[(wid * 64 + j * 8) * 64], 16, 0,
            0);
      *(usx8*)&Bsh[bwG] = cvt8(rg0, rg1);
      *(usx8*)&Bsh[bwL] = cvt8(rl0, rl1);
      __syncthreads();  // stage visible (A from L2 ~300cy exposed; accepted)
      if (t + 1 < NT) {  // B(t+1) regs: issued now, consumed next iter
        const int kf = (t + 1) * BK;
        rg0 = *(const fx4*)(srcG + kf);
        rg1 = *(const fx4*)(srcG + kf + 4);
        rl0 = *(const fx4*)(srcL + kf);
        rl1 = *(const fx4*)(srcL + kf + 4);
      }
      #pragma unroll
      for (int ks = 0; ks < 2; ++ks) {
        const int rk = ks * 4 + fq;
        const int off = (rk ^ (fr & 7)) * 8;
        sx8 aF[8], bG[2], bL[2];
        #pragma unroll
        for (int m = 0; m < 8; ++m)
          aF[m] = *(const sx8*)&Ash[(wm * 128 + m * 16 + fr) * 64 + off];
        #pragma unroll
        for (int n = 0; n < 2; ++n) {
          bG[n] = *(const sx8*)&Bsh[(wn * 32 + n * 16 + fr) * 64 + off];
          bL[n] = *(const sx8*)&Bsh[(64 + wn * 32 + n * 16 + fr) * 64 + off];
        }
        __builtin_amdgcn_s_setprio(1);
        #pragma unroll
        for (int n = 0; n < 2; ++n)
          #pragma unroll
          for (int m = 0; m < 8; ++m) {
            accG[m][n] = MFMA16(aF[m], bG[n], accG[m][n]);
            accL[m][n] = MFMA16(aF[m], bL[n], accL[m][n]);
          }
        __builtin_amdgcn_s_setprio(0);
      }
    }
    __syncthreads();  // done with LDS before next m-pass restages

    #pragma unroll
    for (int n = 0; n < 2; ++n) {
      const int col = c0 + wn * 32 + n * 16 + fr;
      const float bg = b_gate_up[e * (2 * IDIM) + col];
      const float bl = b_gate_up[e * (2 * IDIM) + IDIM + col];
      #pragma unroll
      for (int m = 0; m < 8; ++m) {
        #pragma unroll
        for (int r = 0; r < 4; ++r) {
          int slot = m0 + wm * 128 + m * 16 + fq * 4 + r;
          if (slot < ce) {
            float gv = accG[m][n][r] + bg;
            float lv = accL[m][n][r] + bl;
            float a = gv * (1.0f / (1.0f + __expf(-1.702f * gv))) * (lv + 1.0f);
            act_bf[((size_t)e * NTOK + slot) * IDIM + col] = f2bf(a);
          }
        }
      }
    }
  }
}

// GEMM2: BM=512 x 96 cols; B = w_down fp32 read once globally; A = act_bf
// bf16 DMA (L2-resident per XCD). Same schedule.
__global__ __launch_bounds__(512, 1) void gemm2_k(
    const unsigned short* __restrict__ act_bf, const float* __restrict__ w_down,
    const float* __restrict__ b_down, const int* __restrict__ cnt,
    const int* __restrict__ tok, const float* __restrict__ wgt,
    float* __restrict__ out) {
  const int h = blockIdx.x;
  const int e = h & 7;
  const int c0 = (h >> 3) * 96;  // 30 slices x 96 cols
  const int ce = cnt[e];

  const int tid = threadIdx.x, lane = tid & 63, wid = tid >> 6;
  const int fr = lane & 15, fq = lane >> 4;
  const int wm = wid >> 1, wn = wid & 1;
  const int sw = ((lane & 7) ^ ((lane >> 3) & 7)) * 8;

  __shared__ __align__(16) unsigned short Ash[512 * 64];  // 64 KB
  __shared__ __align__(16) unsigned short Bsh[96 * 64];   // 12 KB

  // B: 96 rows x 8 chunks = 768 slots; thread: slot tid, and (tid<256) 512+tid
  const int bR0 = tid >> 3, bC0 = tid & 7;
  const int bR1 = (tid + 512) >> 3;  // 64..95 for tid<256
  const float* wb = w_down + (size_t)e * HDIM * IDIM;
  const float* srcB0 = wb + (size_t)(c0 + bR0) * IDIM + bC0 * 8;
  const float* srcB1 = wb + (size_t)(c0 + bR1) * IDIM + bC0 * 8;
  const int bw0 = bR0 * 64 + ((bC0 ^ (bR0 & 7)) * 8);
  const int bw1 = bR1 * 64 + ((bC0 ^ (bR1 & 7)) * 8);

  for (int m0 = 0; m0 < ce; m0 += 512) {
    const unsigned short* gA[8];
    #pragma unroll
    for (int j = 0; j < 8; ++j) {
      int R = m0 + wid * 64 + j * 8 + (lane >> 3);
      int rc = R < ce ? R : ce - 1;
      gA[j] = act_bf + ((size_t)e * NTOK + rc) * IDIM + sw;
    }
    const fx4 FZ = {0.f, 0.f, 0.f, 0.f};
    fx4 acc[8][3];
    #pragma unroll
    for (int m = 0; m < 8; m++)
      #pragma unroll
      for (int n = 0; n < 3; n++) acc[m][n] = FZ;

    fx4 r0a = *(const fx4*)(srcB0), r0b = *(const fx4*)(srcB0 + 4);
    fx4 r1a, r1b;
    if (tid < 256) { r1a = *(const fx4*)(srcB1); r1b = *(const fx4*)(srcB1 + 4); }

    for (int t = 0; t < NT; ++t) {
      const int ko = t * BK;
      __syncthreads();
      #pragma unroll
      for (int j = 0; j < 8; ++j)
        __builtin_amdgcn_global_load_lds(
            (gas_p)(gA[j] + ko), (las_p)&Ash[(wid * 64 + j * 8) * 64], 16, 0,
            0);
      *(usx8*)&Bsh[bw0] = cvt8(r0a, r0b);
      if (tid < 256) *(usx8*)&Bsh[bw1] = cvt8(r1a, r1b);
      __syncthreads();
      if (t + 1 < NT) {
        const int kf = (t + 1) * BK;
        r0a = *(const fx4*)(srcB0 + kf);
        r0b = *(const fx4*)(srcB0 + kf + 4);
        if (tid < 256) {
          r1a = *(const fx4*)(srcB1 + kf);
          r1b = *(const fx4*)(srcB1 + kf + 4);
        }
      }
      #pragma unroll
      for (int ks = 0; ks < 2; ++ks) {
        const int rk = ks * 4 + fq;
        const int off = (rk ^ (fr & 7)) * 8;
        sx8 aF[8], bB[3];
        #pragma unroll
        for (int m = 0; m < 8; ++m)
          aF[m] = *(const sx8*)&Ash[(wm * 128 + m * 16 + fr) * 64 + off];
        #pragma unroll
        for (int n = 0; n < 3; ++n)
          bB[n] = *(const sx8*)&Bsh[(wn * 48 + n * 16 + fr) * 64 + off];
        __builtin_amdgcn_s_setprio(1);
        #pragma unroll
        for (int n = 0; n < 3; ++n)
          #pragma unroll
          for (int m = 0; m < 8; ++m)
            acc[m][n] = MFMA16(aF[m], bB[n], acc[m][n]);
        __builtin_amdgcn_s_setprio(0);
      }
    }
    __syncthreads();

    #pragma unroll
    for (int n = 0; n < 3; ++n) {
      const int col = c0 + wn * 48 + n * 16 + fr;
      const float bias = b_down[e * HDIM + col];
      #pragma unroll
      for (int m = 0; m < 8; ++m) {
        #pragma unroll
        for (int r = 0; r < 4; ++r) {
          int slot = m0 + wm * 128 + m * 16 + fq * 4 + r;
          if (slot < ce) {
            int token = tok[e * NTOK + slot];
            float w = wgt[e * NTOK + slot];
            atomicAdd(&out[(size_t)token * HDIM + col],
                      w * (acc[m][n][r] + bias));
          }
        }
      }
    }
  }
}

extern "C" void kernel_launch(void* const* d_in, const int* in_sizes, int n_in,
                              void* d_out, int out_size, void* d_ws,
                              size_t ws_size, hipStream_t stream) {
  const float* x = (const float*)d_in[0];
  const float* norm_w = (const float*)d_in[1];
  const float* gate_w = (const float*)d_in[2];
  const float* gate_b = (const float*)d_in[3];
  const float* w_gate_up = (const float*)d_in[4];
  const float* b_gate_up = (const float*)d_in[5];
  const float* w_down = (const float*)d_in[6];
  const float* b_down = (const float*)d_in[7];
  float* out = (float*)d_out;

  char* ws = (char*)d_ws;
  size_t off = 0;
  unsigned short* t_bf = (unsigned short*)(ws + off);
  off += (size_t)NTOK * HDIM * 2;
  unsigned short* act_bf = (unsigned short*)(ws + off);
  off += (size_t)NEXP * NTOK * IDIM * 2;
  int* cnt = (int*)(ws + off);
  off += 256;
  int* tok = (int*)(ws + off);
  off += (size_t)NEXP * NTOK * 4;
  float* wgt = (float*)(ws + off);

  hipMemsetAsync(cnt, 0, NEXP * sizeof(int), stream);
  init_out_k<<<2880, 256, 0, stream>>>(x, out);
  rms_router_k<<<NTOK, 256, 0, stream>>>(x, norm_w, gate_w, gate_b, t_bf, cnt,
                                         tok, wgt);
  // BM=512 covers a whole expert (m-loop handles ce>512): every weight byte
  // is read by exactly ONE block -> fp32 fetch-once, no prepass, no twins.
  gemm1_k<<<45 * 8, 512, 0, stream>>>(t_bf, w_gate_up, b_gate_up, cnt, tok,
                                      act_bf);
  gemm2_k<<<30 * 8, 512, 0, stream>>>(act_bf, w_down, b_down, cnt, tok, wgt,
                                      out);
}

// Round 15
// 561.838 us; speedup vs baseline: 1.6237x; 1.3710x over previous
//
#include <hip/hip_runtime.h>
#include <hip/hip_bf16.h>

#define NTOK 1024
#define HDIM 2880
#define IDIM 2880
#define NEXP 8
#define BK 64
#define NT 45  // HDIM/BK

typedef __attribute__((ext_vector_type(4))) float fx4;
typedef __attribute__((ext_vector_type(8))) short sx8;
typedef __attribute__((ext_vector_type(8))) unsigned short usx8;

typedef const __attribute__((address_space(1))) void* gas_p;
typedef __attribute__((address_space(3))) void* las_p;

__device__ __forceinline__ unsigned short f2bf(float f) {
  __hip_bfloat16 b = __float2bfloat16(f);
  return __builtin_bit_cast(unsigned short, b);
}
__device__ __forceinline__ usx8 cvt8(fx4 a, fx4 b) {
  usx8 u = {f2bf(a.x), f2bf(a.y), f2bf(a.z), f2bf(a.w),
            f2bf(b.x), f2bf(b.y), f2bf(b.z), f2bf(b.w)};
  return u;
}
__device__ __forceinline__ float bf2f(unsigned short u) {
  unsigned v = ((unsigned)u) << 16;
  return __builtin_bit_cast(float, v);
}

#define MFMA16(a, b, c) __builtin_amdgcn_mfma_f32_16x16x32_bf16(a, b, c, 0, 0, 0)

__global__ __launch_bounds__(256) void rms_router_k(
    const float* __restrict__ x, const float* __restrict__ norm_w,
    const float* __restrict__ gate_w, const float* __restrict__ gate_b,
    unsigned short* __restrict__ t_bf, int* __restrict__ cnt,
    int* __restrict__ tok, int* __restrict__ tokE, int* __restrict__ tokS,
    float* __restrict__ tokW) {
  const int n = blockIdx.x;
  const int tid = threadIdx.x;
  const int wid = tid >> 6, lane = tid & 63;
  const float* xr = x + (size_t)n * HDIM;

  float ss = 0.f;
  for (int h = tid; h < HDIM; h += 256) { float v = xr[h]; ss += v * v; }
  #pragma unroll
  for (int o = 32; o > 0; o >>= 1) ss += __shfl_down(ss, o);
  __shared__ float sred[4];
  if (lane == 0) sred[wid] = ss;
  __syncthreads();
  const float rstd =
      rsqrtf((sred[0] + sred[1] + sred[2] + sred[3]) * (1.0f / HDIM) + 1e-5f);

  float p[NEXP];
  #pragma unroll
  for (int e = 0; e < NEXP; e++) p[e] = 0.f;
  for (int h = tid; h < HDIM; h += 256) {
    float xv = xr[h] * norm_w[h];
    t_bf[(size_t)n * HDIM + h] = f2bf(xv * rstd);
    #pragma unroll
    for (int e = 0; e < NEXP; e++) p[e] += xv * gate_w[e * HDIM + h];
  }
  __shared__ float pls[4][NEXP];
  #pragma unroll
  for (int e = 0; e < NEXP; e++) {
    float v = p[e];
    #pragma unroll
    for (int o = 32; o > 0; o >>= 1) v += __shfl_down(v, o);
    if (lane == 0) pls[wid][e] = v;
  }
  __syncthreads();
  if (tid == 0) {
    float lg[NEXP];
    #pragma unroll
    for (int e = 0; e < NEXP; e++)
      lg[e] = (pls[0][e] + pls[1][e] + pls[2][e] + pls[3][e]) * rstd + gate_b[e];
    unsigned used = 0;
    float val[4];
    int idx[4];
    for (int k = 0; k < 4; k++) {
      float best = -1e30f;
      int bi = 0;
      for (int e = 0; e < NEXP; e++)
        if (!((used >> e) & 1u) && lg[e] > best) { best = lg[e]; bi = e; }
      used |= 1u << bi;
      val[k] = best;
      idx[k] = bi;
    }
    float sum = 0.f, w[4];
    for (int k = 0; k < 4; k++) { w[k] = expf(val[k] - val[0]); sum += w[k]; }
    for (int k = 0; k < 4; k++) {
      int e = idx[k];
      int slot = atomicAdd(&cnt[e], 1);
      tok[e * NTOK + slot] = n;
      tokE[n * 4 + k] = e;
      tokS[n * 4 + k] = slot;
      tokW[n * 4 + k] = w[k] / sum;
    }
  }
}

// Dense-pack gathered token rows: a_pack[e, slot] = t_bf[tok[e,slot]];
// zero-fill slots [ce, ceil128(ce)) so GEMM1 A-DMA needs no clamping.
__global__ __launch_bounds__(256) void pack_k(
    const unsigned short* __restrict__ t_bf, const int* __restrict__ cnt,
    const int* __restrict__ tok, unsigned short* __restrict__ a_pack) {
  const int e = blockIdx.x >> 8;          // 256 blocks/expert, 4 rows each
  const int r0 = (blockIdx.x & 255) * 4;
  const int ce = cnt[e];
  const int lim = (ce + 127) & ~127;
  if (r0 >= lim) return;
  const int row = r0 + (threadIdx.x >> 6);
  const int lane = threadIdx.x & 63;
  unsigned short* dst = a_pack + ((size_t)e * NTOK + row) * HDIM;
  if (row < ce) {
    const unsigned short* src = t_bf + (size_t)tok[e * NTOK + row] * HDIM;
    for (int c = lane; c < HDIM / 8; c += 64)
      *(usx8*)(dst + c * 8) = *(const usx8*)(src + c * 8);
  } else {
    const usx8 z = {0, 0, 0, 0, 0, 0, 0, 0};
    for (int c = lane; c < HDIM / 8; c += 64) *(usx8*)(dst + c * 8) = z;
  }
}

// GEMM1 (m97 scaffold): 128 slots x 64 I-cols x {G,L}, BK=64, 4 waves (2x2),
// single-buf 32 KB LDS, 3 blocks/CU. A: DENSE bf16 DMA from a_pack.
// B: fp32 fetch-once, reg-prefetch after ready-barrier, in-loop cvt.
__global__ __launch_bounds__(256, 3) void gemm1_k(
    const unsigned short* __restrict__ a_pack,
    const float* __restrict__ w_gate_up, const float* __restrict__ b_gate_up,
    const int* __restrict__ cnt, unsigned short* __restrict__ act_bf) {
  const int h = blockIdx.x;
  const int u = (h >> 6) * 8 + (h & 7);  // (e, col-slice) < 360
  const int z = (h >> 3) & 7;
  const int e = u / 45;
  const int c0 = (u % 45) * 64;
  const int m0 = z * 128;
  const int ce = cnt[e];
  if (m0 >= ce) return;

  const int tid = threadIdx.x, lane = tid & 63, wid = tid >> 6;
  const int fr = lane & 15, fq = lane >> 4;
  const int wm = wid >> 1, wn = wid & 1;
  const int sw = ((lane & 7) ^ ((lane >> 3) & 7)) * 8;

  __shared__ __align__(16) unsigned short Ash[128 * 64];  // 16 KB
  __shared__ __align__(16) unsigned short Bsh[128 * 64];  // 16 KB (G:0-63 L:64-127)

  const fx4 FZ = {0.f, 0.f, 0.f, 0.f};
  fx4 accG[4][2], accL[4][2];
  #pragma unroll
  for (int m = 0; m < 4; m++)
    #pragma unroll
    for (int n = 0; n < 2; n++) { accG[m][n] = FZ; accL[m][n] = FZ; }

  // A: dense consecutive rows; 4 DMA/thread, 8 rows per instr.
  const unsigned short* gA[4];
  #pragma unroll
  for (int j = 0; j < 4; ++j) {
    int row = m0 + wid * 32 + j * 8 + (lane >> 3);
    gA[j] = a_pack + ((size_t)e * NTOK + row) * HDIM + sw;
  }
  // B: 128 rows (64 G + 64 L) x 8 chunks = 1024 slots; 4 slots/thread.
  const float* fB[4];
  int bO[4];
  #pragma unroll
  for (int q = 0; q < 4; ++q) {
    int s = tid + 256 * q;
    int bR = s >> 3, bC = s & 7;
    int wr = bR < 64 ? (c0 + bR) : (IDIM + c0 + (bR - 64));
    fB[q] = w_gate_up + ((size_t)e * (2 * IDIM) + wr) * HDIM + bC * 8;
    bO[q] = bR * 64 + ((bC ^ (bR & 7)) * 8);
  }

  fx4 Ra[8];
  #pragma unroll
  for (int q = 0; q < 4; ++q) {
    Ra[2 * q] = *(const fx4*)(fB[q]);
    Ra[2 * q + 1] = *(const fx4*)(fB[q] + 4);
  }

  for (int t = 0; t < NT; ++t) {
    const int ko = t * BK;
    __syncthreads();  // previous tile consumed
    #pragma unroll
    for (int j = 0; j < 4; ++j)
      __builtin_amdgcn_global_load_lds((gas_p)(gA[j] + ko),
                                       (las_p)&Ash[(wid * 32 + j * 8) * 64], 16,
                                       0, 0);
    #pragma unroll
    for (int q = 0; q < 4; ++q)
      *(usx8*)&Bsh[bO[q]] = cvt8(Ra[2 * q], Ra[2 * q + 1]);
    __syncthreads();  // tile ready (A-DMA drain covered by co-resident blocks)
    if (t + 1 < NT) {
      const int kf = (t + 1) * BK;
      #pragma unroll
      for (int q = 0; q < 4; ++q) {
        Ra[2 * q] = *(const fx4*)(fB[q] + kf);
        Ra[2 * q + 1] = *(const fx4*)(fB[q] + kf + 4);
      }
    }
    #pragma unroll
    for (int ks = 0; ks < 2; ++ks) {
      const int off = ((ks * 4 + fq) ^ (fr & 7)) * 8;
      sx8 aF[4], bG[2], bL[2];
      #pragma unroll
      for (int m = 0; m < 4; ++m)
        aF[m] = *(const sx8*)&Ash[(wm * 64 + m * 16 + fr) * 64 + off];
      #pragma unroll
      for (int n = 0; n < 2; ++n) {
        bG[n] = *(const sx8*)&Bsh[(wn * 32 + n * 16 + fr) * 64 + off];
        bL[n] = *(const sx8*)&Bsh[(64 + wn * 32 + n * 16 + fr) * 64 + off];
      }
      __builtin_amdgcn_s_setprio(1);
      #pragma unroll
      for (int n = 0; n < 2; ++n)
        #pragma unroll
        for (int m = 0; m < 4; ++m) {
          accG[m][n] = MFMA16(aF[m], bG[n], accG[m][n]);
          accL[m][n] = MFMA16(aF[m], bL[n], accL[m][n]);
        }
      __builtin_amdgcn_s_setprio(0);
    }
  }

  #pragma unroll
  for (int n = 0; n < 2; ++n) {
    const int col = c0 + wn * 32 + n * 16 + fr;
    const float bg = b_gate_up[e * (2 * IDIM) + col];
    const float bl = b_gate_up[e * (2 * IDIM) + IDIM + col];
    #pragma unroll
    for (int m = 0; m < 4; ++m) {
      #pragma unroll
      for (int r = 0; r < 4; ++r) {
        int slot = m0 + wm * 64 + m * 16 + fq * 4 + r;
        if (slot < ce) {
          float gv = accG[m][n][r] + bg;
          float lv = accL[m][n][r] + bl;
          float a = gv * (1.0f / (1.0f + __expf(-1.702f * gv))) * (lv + 1.0f);
          act_bf[((size_t)e * NTOK + slot) * IDIM + col] = f2bf(a);
        }
      }
    }
  }
}

// GEMM2 (m97 scaffold): 128 slots x 96 cols, BK=64, 4 waves (2x2),
// single-buf 28 KB, 3 blocks/CU. Dense A; NO atomics: writes outs_bf[e,slot].
__global__ __launch_bounds__(256, 3) void gemm2_k(
    const unsigned short* __restrict__ act_bf, const float* __restrict__ w_down,
    const float* __restrict__ b_down, const int* __restrict__ cnt,
    unsigned short* __restrict__ outs_bf) {
  const int h = blockIdx.x;
  const int u = (h >> 6) * 8 + (h & 7);  // < 240
  const int z = (h >> 3) & 7;
  const int e = u / 30;
  const int c0 = (u % 30) * 96;
  const int m0 = z * 128;
  const int ce = cnt[e];
  if (m0 >= ce) return;

  const int tid = threadIdx.x, lane = tid & 63, wid = tid >> 6;
  const int fr = lane & 15, fq = lane >> 4;
  const int wm = wid >> 1, wn = wid & 1;
  const int sw = ((lane & 7) ^ ((lane >> 3) & 7)) * 8;

  __shared__ __align__(16) unsigned short Ash[128 * 64];  // 16 KB
  __shared__ __align__(16) unsigned short Bsh[96 * 64];   // 12 KB

  const fx4 FZ = {0.f, 0.f, 0.f, 0.f};
  fx4 acc[4][3];
  #pragma unroll
  for (int m = 0; m < 4; m++)
    #pragma unroll
    for (int n = 0; n < 3; n++) acc[m][n] = FZ;

  const unsigned short* gA[4];
  #pragma unroll
  for (int j = 0; j < 4; ++j) {
    int row = m0 + wid * 32 + j * 8 + (lane >> 3);
    gA[j] = act_bf + ((size_t)e * NTOK + row) * IDIM + sw;
  }
  // B: 96 rows x 8 chunks = 768 slots; 3 slots/thread.
  const float* fB[3];
  int bO[3];
  #pragma unroll
  for (int q = 0; q < 3; ++q) {
    int s = tid + 256 * q;
    int bR = s >> 3, bC = s & 7;
    fB[q] = w_down + ((size_t)e * HDIM + c0 + bR) * IDIM + bC * 8;
    bO[q] = bR * 64 + ((bC ^ (bR & 7)) * 8);
  }

  fx4 Ra[6];
  #pragma unroll
  for (int q = 0; q < 3; ++q) {
    Ra[2 * q] = *(const fx4*)(fB[q]);
    Ra[2 * q + 1] = *(const fx4*)(fB[q] + 4);
  }

  for (int t = 0; t < NT; ++t) {
    const int ko = t * BK;
    __syncthreads();
    #pragma unroll
    for (int j = 0; j < 4; ++j)
      __builtin_amdgcn_global_load_lds((gas_p)(gA[j] + ko),
                                       (las_p)&Ash[(wid * 32 + j * 8) * 64], 16,
                                       0, 0);
    #pragma unroll
    for (int q = 0; q < 3; ++q)
      *(usx8*)&Bsh[bO[q]] = cvt8(Ra[2 * q], Ra[2 * q + 1]);
    __syncthreads();
    if (t + 1 < NT) {
      const int kf = (t + 1) * BK;
      #pragma unroll
      for (int q = 0; q < 3; ++q) {
        Ra[2 * q] = *(const fx4*)(fB[q] + kf);
        Ra[2 * q + 1] = *(const fx4*)(fB[q] + kf + 4);
      }
    }
    #pragma unroll
    for (int ks = 0; ks < 2; ++ks) {
      const int off = ((ks * 4 + fq) ^ (fr & 7)) * 8;
      sx8 aF[4], bB[3];
      #pragma unroll
      for (int m = 0; m < 4; ++m)
        aF[m] = *(const sx8*)&Ash[(wm * 64 + m * 16 + fr) * 64 + off];
      #pragma unroll
      for (int n = 0; n < 3; ++n)
        bB[n] = *(const sx8*)&Bsh[(wn * 48 + n * 16 + fr) * 64 + off];
      __builtin_amdgcn_s_setprio(1);
      #pragma unroll
      for (int n = 0; n < 3; ++n)
        #pragma unroll
        for (int m = 0; m < 4; ++m)
          acc[m][n] = MFMA16(aF[m], bB[n], acc[m][n]);
      __builtin_amdgcn_s_setprio(0);
    }
  }

  #pragma unroll
  for (int n = 0; n < 3; ++n) {
    const int col = c0 + wn * 48 + n * 16 + fr;
    const float bias = b_down[e * HDIM + col];
    #pragma unroll
    for (int m = 0; m < 4; ++m) {
      #pragma unroll
      for (int r = 0; r < 4; ++r) {
        int slot = m0 + wm * 64 + m * 16 + fq * 4 + r;
        if (slot < ce)
          outs_bf[((size_t)e * NTOK + slot) * HDIM + col] =
              f2bf(acc[m][n][r] + bias);
      }
    }
  }
}

// combine: out[n] = x[n] + sum_k w_k * outs_bf[e_k, s_k]
__global__ __launch_bounds__(256) void combine_k(
    const float* __restrict__ x, const unsigned short* __restrict__ outs_bf,
    const int* __restrict__ tokE, const int* __restrict__ tokS,
    const float* __restrict__ tokW, float* __restrict__ out) {
  const int n = blockIdx.x;
  const unsigned short* src[4];
  float w[4];
  #pragma unroll
  for (int k = 0; k < 4; ++k) {
    int e = tokE[n * 4 + k], s = tokS[n * 4 + k];
    w[k] = tokW[n * 4 + k];
    src[k] = outs_bf + ((size_t)e * NTOK + s) * HDIM;
  }
  const float* xr = x + (size_t)n * HDIM;
  float* orow = out + (size_t)n * HDIM;
  for (int c = threadIdx.x; c < HDIM / 8; c += 256) {
    fx4 lo = *(const fx4*)(xr + c * 8);
    fx4 hi = *(const fx4*)(xr + c * 8 + 4);
    #pragma unroll
    for (int k = 0; k < 4; ++k) {
      usx8 v = *(const usx8*)(src[k] + c * 8);
      lo.x += w[k] * bf2f(v[0]);
      lo.y += w[k] * bf2f(v[1]);
      lo.z += w[k] * bf2f(v[2]);
      lo.w += w[k] * bf2f(v[3]);
      hi.x += w[k] * bf2f(v[4]);
      hi.y += w[k] * bf2f(v[5]);
      hi.z += w[k] * bf2f(v[6]);
      hi.w += w[k] * bf2f(v[7]);
    }
    *(fx4*)(orow + c * 8) = lo;
    *(fx4*)(orow + c * 8 + 4) = hi;
  }
}

extern "C" void kernel_launch(void* const* d_in, const int* in_sizes, int n_in,
                              void* d_out, int out_size, void* d_ws,
                              size_t ws_size, hipStream_t stream) {
  const float* x = (const float*)d_in[0];
  const float* norm_w = (const float*)d_in[1];
  const float* gate_w = (const float*)d_in[2];
  const float* gate_b = (const float*)d_in[3];
  const float* w_gate_up = (const float*)d_in[4];
  const float* b_gate_up = (const float*)d_in[5];
  const float* w_down = (const float*)d_in[6];
  const float* b_down = (const float*)d_in[7];
  float* out = (float*)d_out;

  char* ws = (char*)d_ws;
  size_t off = 0;
  unsigned short* t_bf = (unsigned short*)(ws + off);
  off += (size_t)NTOK * HDIM * 2;
  unsigned short* a_pack = (unsigned short*)(ws + off);
  off += (size_t)NEXP * NTOK * HDIM * 2;
  unsigned short* act_bf = (unsigned short*)(ws + off);
  off += (size_t)NEXP * NTOK * IDIM * 2;
  unsigned short* outs_bf = (unsigned short*)(ws + off);
  off += (size_t)NEXP * NTOK * HDIM * 2;
  int* cnt = (int*)(ws + off);
  off += 256;
  int* tok = (int*)(ws + off);
  off += (size_t)NEXP * NTOK * 4;
  int* tokE = (int*)(ws + off);
  off += (size_t)NTOK * 4 * 4;
  int* tokS = (int*)(ws + off);
  off += (size_t)NTOK * 4 * 4;
  float* tokW = (float*)(ws + off);
  off += (size_t)NTOK * 4 * 4;

  hipMemsetAsync(cnt, 0, NEXP * sizeof(int), stream);
  rms_router_k<<<NTOK, 256, 0, stream>>>(x, norm_w, gate_w, gate_b, t_bf, cnt,
                                         tok, tokE, tokS, tokW);
  pack_k<<<NEXP * 256, 256, 0, stream>>>(t_bf, cnt, tok, a_pack);
  // h = g*64 + z*8 + v : z-twins of one (e,c) share h%8 (same XCD) within a
  // 64-block window -> concurrent -> weight panel fetched from HBM once.
  gemm1_k<<<2880, 256, 0, stream>>>(a_pack, w_gate_up, b_gate_up, cnt, act_bf);
  gemm2_k<<<1920, 256, 0, stream>>>(act_bf, w_down, b_down, cnt, outs_bf);
  combine_k<<<NTOK, 256, 0, stream>>>(x, outs_bf, tokE, tokS, tokW, out);
}